// Round 12
// baseline (894.264 us; speedup 1.0000x reference)
//
#include <hip/hip_runtime.h>
#include <math.h>

#define S 512
#define DIN 256
#define H 512

// native vector type for 16B stores
typedef float f4 __attribute__((ext_vector_type(4)));

// Quad-row block stats over 512 threads (1 value per row per thread).
// Butterfly within wave, 8 wave-partials per row in LDS, thread0 finalizes.
// red needs 72 floats.
__device__ __forceinline__ void block_stats4_512(const float* v, float* red,
                                                 float* m, float* inv)
{
    float s[4], ss[4];
    #pragma unroll
    for (int rr = 0; rr < 4; ++rr) { s[rr] = v[rr]; ss[rr] = v[rr] * v[rr]; }
    for (int off = 32; off > 0; off >>= 1) {
        #pragma unroll
        for (int rr = 0; rr < 4; ++rr) {
            s[rr]  += __shfl_down(s[rr], off);
            ss[rr] += __shfl_down(ss[rr], off);
        }
    }
    int wid = threadIdx.x >> 6;   // 0..7
    if ((threadIdx.x & 63) == 0) {
        #pragma unroll
        for (int rr = 0; rr < 4; ++rr) {
            red[rr * 8 + wid]      = s[rr];
            red[32 + rr * 8 + wid] = ss[rr];
        }
    }
    __syncthreads();
    if (threadIdx.x == 0) {
        #pragma unroll
        for (int rr = 0; rr < 4; ++rr) {
            float S0 = 0.0f, SS0 = 0.0f;
            #pragma unroll
            for (int w = 0; w < 8; ++w) { S0 += red[rr * 8 + w]; SS0 += red[32 + rr * 8 + w]; }
            float mm = S0 * (1.0f / 512.0f);
            red[64 + rr] = mm;
            red[68 + rr] = rsqrtf(SS0 * (1.0f / 512.0f) - mm * mm + 1e-5f);
        }
    }
    __syncthreads();
    #pragma unroll
    for (int rr = 0; rr < 4; ++rr) { m[rr] = red[64 + rr]; inv[rr] = red[68 + rr]; }
}

// ---------------------------------------------------------------------------
// Kernel 1 (was 2): fused sort + per-row encoder — ROUND 12:
//  - SORT FOLDED IN: each block redundantly computes the full stable rank
//    map in LDS (O(S^2)=262k compares, ~3 us/block) -> sort_kernel dispatch
//    + launch gap + order/ts_s/amp_s global round-trip eliminated.
//  - PE via sincos recurrence: 2 sincosf + 3 rotations instead of 4 libm
//    trig calls per thread (rotation err ~1e-6 << tolerance).
//  - 4 rows/block, 512 threads, 128 blocks (r10 config, kept).
// ---------------------------------------------------------------------------
__global__ __launch_bounds__(512) void encoder_kernel(
    const float* __restrict__ ts, const float* __restrict__ amp,
    const float* __restrict__ feats,
    const float* __restrict__ We1, const float* __restrict__ be1,
    const float* __restrict__ We2, const float* __restrict__ be2,
    const float* __restrict__ g_ev, const float* __restrict__ b_ev,
    const float* __restrict__ Wt1, const float* __restrict__ bt1,
    const float* __restrict__ Wt2, const float* __restrict__ bt2,
    const float* __restrict__ Wc, const float* __restrict__ bc,
    const float* __restrict__ g_sr, const float* __restrict__ b_sr,
    float* __restrict__ ctx)
{
    __shared__ float sts_in[S];     // original-order timestamps
    __shared__ float stso[S];       // rank-sorted timestamps
    __shared__ float sampo[S];      // rank-sorted amplitudes
    __shared__ int   sorder[S];     // rank -> original index
    __shared__ float sf[4][DIN];
    __shared__ float sh1[4][256];
    __shared__ float sth[4][128];
    __shared__ float scomb[4][1024];
    __shared__ float red[72];

    int r0 = blockIdx.x * 4;
    int t  = threadIdx.x;          // 0..511 == original event index

    // ---- in-block stable rank sort (identical formula to jnp.argsort) ----
    sts_in[t] = ts[t];
    float av = amp[t];
    __syncthreads();
    {
        float ti = sts_in[t];
        int rank = 0;
        for (int j = 0; j < S; ++j) {
            float tj = sts_in[j];
            rank += (tj < ti) || (tj == ti && j < t);
        }
        sorder[rank] = t;
        stso[rank]   = ti;
        sampo[rank]  = av;
    }
    __syncthreads();

    // per-row scalars
    float aa[4];
    aa[0] = sampo[r0];     aa[1] = sampo[r0 + 1];
    aa[2] = sampo[r0 + 2]; aa[3] = sampo[r0 + 3];
    float x0 = stso[r0],     x1 = stso[r0 + 1];
    float x2 = stso[r0 + 2], x3 = stso[r0 + 3];

    // feature load: thread (rp = t>>8, c = t&255) loads rows rp and rp+2
    {
        int rp = t >> 8, c = t & 255;
        sf[rp][c]     = feats[sorder[r0 + rp] * DIN + c];
        sf[rp + 2][c] = feats[sorder[r0 + rp + 2] * DIN + c];
    }
    // temporal layer 1: row = t>>7 (0..3), c = t&127
    {
        int rw = t >> 7, c = t & 127;
        float xv = (rw & 2) ? ((rw & 1) ? x3 : x2) : ((rw & 1) ? x1 : x0);
        sth[rw][c] = fmaxf(fmaf(xv, Wt1[c], bt1[c]), 0.0f);
    }
    __syncthreads();

    // hidden1 = relu(sf @ We1 + be1): thread covers (rp, c) and (rp+2, c),
    // sharing each We1 dword across 2 rows
    {
        int rp = t >> 8, c = t & 255;
        float a0 = be1[c], a1 = be1[c];
        #pragma unroll 4
        for (int d = 0; d < DIN; ++d) {
            float w = We1[d * 256 + c];
            a0 = fmaf(sf[rp][d],     w, a0);
            a1 = fmaf(sf[rp + 2][d], w, a1);
        }
        sh1[rp][c]     = fmaxf(a0, 0.0f);
        sh1[rp + 2][c] = fmaxf(a1, 0.0f);
    }
    __syncthreads();

    // h = sh1 @ We2 + be2: thread t = col t for ALL 4 rows (4x weight reuse)
    float h[4];
    {
        float b = be2[t];
        h[0] = b; h[1] = b; h[2] = b; h[3] = b;
    }
    #pragma unroll 4
    for (int k = 0; k < 256; ++k) {
        float w = We2[k * 512 + t];
        #pragma unroll
        for (int rr = 0; rr < 4; ++rr) h[rr] = fmaf(sh1[rr][k], w, h[rr]);
    }
    float m[4], inv[4];
    block_stats4_512(h, red, m, inv);
    #pragma unroll
    for (int rr = 0; rr < 4; ++rr)
        scomb[rr][t] = fmaf((h[rr] - m[rr]) * inv[rr], g_ev[t], b_ev[t]) * aa[rr];

    // temporal layer 2: thread covers (rp, c) and (rp+2, c), shared Wt2 dword
    {
        int rp = t >> 8, c = t & 255;
        float tv0 = bt2[c], tv1 = bt2[c];
        #pragma unroll 4
        for (int k = 0; k < 128; ++k) {
            float w = Wt2[k * 256 + c];
            tv0 = fmaf(sth[rp][k],     w, tv0);
            tv1 = fmaf(sth[rp + 2][k], w, tv1);
        }
        tv0 *= (rp ? aa[1] : aa[0]);
        tv1 *= (rp ? aa[3] : aa[2]);
        scomb[rp][512 + c]     = tv0;
        scomb[rp][768 + c]     = tv0;
        scomb[rp + 2][512 + c] = tv1;
        scomb[rp + 2][768 + c] = tv1;
    }
    __syncthreads();

    // comb @ Wc + bc: thread t = col t, 4 rows share each Wc dword
    float c4[4];
    {
        float b = bc[t];
        c4[0] = b; c4[1] = b; c4[2] = b; c4[3] = b;
    }
    #pragma unroll 4
    for (int u = 0; u < 1024; ++u) {
        float w = Wc[u * 512 + t];
        #pragma unroll
        for (int rr = 0; rr < 4; ++rr) c4[rr] = fmaf(scomb[rr][u], w, c4[rr]);
    }
    float n[4], jnv[4];
    block_stats4_512(c4, red, n, jnv);

    // LN + sinusoidal PE + store.
    // Angles for rr=0..3 form an arithmetic progression with step df:
    // one sincosf(a0) + one sincosf(df), then 2-FMA rotations.
    const float NEG_LN1E4_OVER_H = -9.210340371976184f / 512.0f;
    float df = expf((float)(2 * (t >> 1)) * NEG_LN1E4_OVER_H);
    float s0, c0, sd, cd;
    sincosf((float)r0 * df, &s0, &c0);
    sincosf(df, &sd, &cd);
    bool use_cos = (t & 1);
    #pragma unroll
    for (int rr = 0; rr < 4; ++rr) {
        float e = fmaf((c4[rr] - n[rr]) * jnv[rr], g_sr[t], b_sr[t]);
        e += use_cos ? c0 : s0;
        ctx[(r0 + rr) * 512 + t] = e;
        float s1 = fmaf(s0, cd, c0 * sd);   // sin(a+df)
        float c1 = fmaf(c0, cd, -s0 * sd);  // cos(a+df)
        s0 = s1; c0 = c1;
    }
}

// ---------------------------------------------------------------------------
// Kernel 2: Q/K/V projections — r10 config, UNCHANGED. 8 rows/block,
// grid (64,2) = 128 blocks, 256 thr, 24 acc/thread, 8x weight reuse.
// ---------------------------------------------------------------------------
__global__ __launch_bounds__(256) void qkv_kernel(
    const float* __restrict__ ctx,
    const float* __restrict__ Wq, const float* __restrict__ bq,
    const float* __restrict__ Wk, const float* __restrict__ bk,
    const float* __restrict__ Wv, const float* __restrict__ bv,
    float* __restrict__ Qout, float* __restrict__ Kbase, float* __restrict__ Vout)
{
    __shared__ float sc[8][512];
    int r0  = blockIdx.x * 8;
    int t   = threadIdx.x;
    int col = blockIdx.y * 256 + t;
    #pragma unroll
    for (int rr = 0; rr < 8; ++rr) {
        sc[rr][t]       = ctx[(r0 + rr) * 512 + t];
        sc[rr][t + 256] = ctx[(r0 + rr) * 512 + t + 256];
    }
    __syncthreads();

    float q[8], k[8], v[8];
    float bqc = bq[col], bkc = bk[col], bvc = bv[col];
    #pragma unroll
    for (int rr = 0; rr < 8; ++rr) { q[rr] = bqc; k[rr] = bkc; v[rr] = bvc; }

    #pragma unroll 2
    for (int h = 0; h < 512; ++h) {
        float wq = Wq[h * 512 + col];
        float wk = Wk[h * 512 + col];
        float wv = Wv[h * 512 + col];
        #pragma unroll
        for (int rr = 0; rr < 8; ++rr) {
            float cv = sc[rr][h];
            q[rr] = fmaf(cv, wq, q[rr]);
            k[rr] = fmaf(cv, wk, k[rr]);
            v[rr] = fmaf(cv, wv, v[rr]);
        }
    }
    #pragma unroll
    for (int rr = 0; rr < 8; ++rr) {
        int r = r0 + rr;
        __builtin_nontemporal_store(q[rr], &Qout[r * 512 + col]);
        Kbase[r * 512 + col] = k[rr];
        __builtin_nontemporal_store(v[rr], &Vout[r * 512 + col]);
    }
}

// ---------------------------------------------------------------------------
// Kernel 3: K[i,j,h] = Kbase[j,h] + 0.1/(1+|i-j|).  537 MB write-bound.
// MEASURED (r4 vs r7): nt=921.4, normal=912.4 -> keep NORMAL stores.
//  - conn LUT in LDS (IEEE div off the store path)
//  - grid (8,512): 8192 waves = 32 waves/CU for store depth
// Fully coalesced 16B stores. UNCHANGED.
// ---------------------------------------------------------------------------
__global__ __launch_bounds__(128) void kexpand_kernel(
    const float* __restrict__ Kbase, float* __restrict__ Kout)
{
    __shared__ float sconn[1024];
    int j  = blockIdx.y;            // 0..511
    int i0 = blockIdx.x * 64;       // i-chunk (8 chunks of 64)
    int t  = threadIdx.x;           // 0..127 -> 16B lane
    #pragma unroll
    for (int k = t; k < 1024; k += 128) sconn[k] = 0.1f / (float)(1 + k);
    f4 kb = ((const f4*)(Kbase + j * 512))[t];
    __syncthreads();
    f4* out = (f4*)Kout;
    size_t base = (size_t)j * 128 + t;
    #pragma unroll 8
    for (int ii = 0; ii < 64; ++ii) {
        int i = i0 + ii;
        int d = i - j; if (d < 0) d = -d;
        float conn = sconn[d];      // uniform addr -> LDS broadcast
        f4 v = kb + conn;
        out[base + (size_t)i * 65536] = v;
    }
}

extern "C" void kernel_launch(void* const* d_in, const int* in_sizes, int n_in,
                              void* d_out, int out_size, void* d_ws, size_t ws_size,
                              hipStream_t stream) {
    const float* timestamps = (const float*)d_in[0];
    const float* features   = (const float*)d_in[1];
    const float* amplitudes = (const float*)d_in[2];
    // d_in[3] = neuron_ids (unused by reference)
    const float* We1 = (const float*)d_in[4];
    const float* be1 = (const float*)d_in[5];
    const float* We2 = (const float*)d_in[6];
    const float* be2 = (const float*)d_in[7];
    const float* g_ev = (const float*)d_in[8];
    const float* b_ev = (const float*)d_in[9];
    const float* Wt1 = (const float*)d_in[10];
    const float* bt1 = (const float*)d_in[11];
    const float* Wt2 = (const float*)d_in[12];
    const float* bt2 = (const float*)d_in[13];
    const float* Wc  = (const float*)d_in[14];
    const float* bc  = (const float*)d_in[15];
    const float* g_sr = (const float*)d_in[16];
    const float* b_sr = (const float*)d_in[17];
    const float* Wq = (const float*)d_in[18];
    const float* bq = (const float*)d_in[19];
    const float* Wk = (const float*)d_in[20];
    const float* bk = (const float*)d_in[21];
    const float* Wv = (const float*)d_in[22];
    const float* bv = (const float*)d_in[23];

    // Output layout: Q [1,512,512] | K [512,512,512] | V [1,512,512]
    float* Qout = (float*)d_out;
    float* Kout = (float*)d_out + 262144;
    float* Vout = (float*)d_out + 262144 + 512 * 512 * 512;

    // Workspace layout (~2.1 MB): ctx | Kbase
    char* ws = (char*)d_ws;
    float* ctx   = (float*)ws;  ws += 262144 * sizeof(float);
    float* Kbase = (float*)ws;

    encoder_kernel<<<128, 512, 0, stream>>>(timestamps, amplitudes, features,
        We1, be1, We2, be2, g_ev, b_ev, Wt1, bt1, Wt2, bt2, Wc, bc, g_sr, b_sr, ctx);
    qkv_kernel<<<dim3(64, 2), 256, 0, stream>>>(ctx, Wq, bq, Wk, bk, Wv, bv, Qout, Kbase, Vout);
    kexpand_kernel<<<dim3(8, 512), 128, 0, stream>>>(Kbase, Kout);
}